// Round 10
// baseline (436.085 us; speedup 1.0000x reference)
//
#include <hip/hip_runtime.h>
#include <hip/hip_bf16.h>

#define EPS_F 1e-10f

typedef short s16x8 __attribute__((ext_vector_type(8)));
typedef float f32x4 __attribute__((ext_vector_type(4)));
typedef unsigned short ushort_t;

constexpr int B_ = 8, S_ = 4, C_ = 512, Cq_ = 128, HW_ = 4096;
constexpr long long D_ = (long long)Cq_ * HW_;

__device__ inline float bf_lo(unsigned int u) { return __uint_as_float(u << 16); }
__device__ inline float bf_hi(unsigned int u) { return __uint_as_float(u & 0xffff0000u); }

__device__ inline ushort_t f2bf(float f) {
    __hip_bfloat16 h = __float2bfloat16(f);
    return *reinterpret_cast<ushort_t*>(&h);
}
__device__ inline unsigned int pack_bf2(float a, float b) {
    return (unsigned int)f2bf(a) | ((unsigned int)f2bf(b) << 16);
}
__device__ inline float dot8(uint4 a, uint4 b) {
    return bf_lo(a.x) * bf_lo(b.x) + bf_hi(a.x) * bf_hi(b.x)
         + bf_lo(a.y) * bf_lo(b.y) + bf_hi(a.y) * bf_hi(b.y)
         + bf_lo(a.z) * bf_lo(b.z) + bf_hi(a.z) * bf_hi(b.z)
         + bf_lo(a.w) * bf_lo(b.w) + bf_hi(a.w) * bf_hi(b.w);
}

#define GLOAD16(gp, lp) __builtin_amdgcn_global_load_lds( \
    (const __attribute__((address_space(1))) unsigned int*)(gp), \
    (__attribute__((address_space(3))) unsigned int*)(lp), 16, 0, 0)

#define VMCNT(n) asm volatile("s_waitcnt vmcnt(" #n ")" ::: "memory")
#define VMCNT0 asm volatile("s_waitcnt vmcnt(0)" ::: "memory")
#define LGK0   asm volatile("s_waitcnt lgkmcnt(0)" ::: "memory")
#define MFMA16(a, b, c) __builtin_amdgcn_mfma_f32_16x16x32_bf16(a, b, c, 0, 0, 0)

// swizzle involution over 8 chunk slots, p in [0,64)
#define SWZ(p) ((((p) >> 3) & 7) ^ ((p) & 7))

// ---------------------------------------------------------------------------
// prep3: fp32->bf16 weights, pre-swizzled (chunk slot = c ^ (row&7)) so
// global_load_lds (linear dest) + swizzled ds_read_b128 is conflict-free.
// Also zeroes g4.
// ---------------------------------------------------------------------------
__global__ __launch_bounds__(256) void prep3(
    const float* __restrict__ wq, const float* __restrict__ wk,
    const float* __restrict__ wv,
    ushort_t* __restrict__ Wqk_pre, ushort_t* __restrict__ Wvb_pre,
    float* __restrict__ g4) {
    int gid = blockIdx.x * 256 + threadIdx.x;
    if (gid < 8 * 24 * 16) g4[gid] = 0.f;
    if (gid < 65536) {                      // Wqk chunks
        int s = gid >> 14;
        int kt = (gid >> 11) & 7;
        int row = (gid >> 3) & 255;
        int slot = gid & 7;
        int col = kt * 64 + ((slot ^ (row & 7)) << 3);
        const float* src = (row < 128)
            ? &wq[((size_t)s * 128 + row) * 512 + col]
            : &wk[((size_t)s * 128 + (row - 128)) * 512 + col];
        float4 f0 = *reinterpret_cast<const float4*>(src);
        float4 f1 = *reinterpret_cast<const float4*>(src + 4);
        uint4 o;
        o.x = pack_bf2(f0.x, f0.y); o.y = pack_bf2(f0.z, f0.w);
        o.z = pack_bf2(f1.x, f1.y); o.w = pack_bf2(f1.z, f1.w);
        *reinterpret_cast<uint4*>(Wqk_pre + (size_t)gid * 8) = o;
    } else {                                 // Wvb chunks
        int c2 = gid - 65536;                // < 131072
        int t = c2 >> 15;
        int ct = (c2 >> 14) & 1;
        int kt = (c2 >> 11) & 7;
        int row = (c2 >> 3) & 255;
        int slot = c2 & 7;
        int col = kt * 64 + ((slot ^ (row & 7)) << 3);
        const float* src = &wv[((size_t)t * 512 + ct * 256 + row) * 512 + col];
        float4 f0 = *reinterpret_cast<const float4*>(src);
        float4 f1 = *reinterpret_cast<const float4*>(src + 4);
        uint4 o;
        o.x = pack_bf2(f0.x, f0.y); o.y = pack_bf2(f0.z, f0.w);
        o.z = pack_bf2(f1.x, f1.y); o.w = pack_bf2(f1.z, f1.w);
        *reinterpret_cast<uint4*>(Wvb_pre + (size_t)c2 * 8) = o;
    }
}

// ===========================================================================
// qk8f: r8's qk8 with ONE change -- EMIT writes xbfF in FRAGMENT-MAJOR order:
// xbfF[bt][ptile(256)][ktile(16)][lane(64)x16B], where a (16p x 32k) MFMA
// B-fragment-tile is 64 lanes x 16B contiguous (lane: li=p, lk=k-chunk).
// vblend10 then loads B-frags DIRECTLY global->VGPR, one coalesced 1KB load.
// ===========================================================================
__global__ __launch_bounds__(512, 8) void qk8f(
    const ushort_t* __restrict__ Wqk_pre, const float* __restrict__ x,
    const float* __restrict__ bq, const float* __restrict__ bk,
    ushort_t* __restrict__ Qb, ushort_t* __restrict__ Kb,
    ushort_t* __restrict__ xbfF) {

    const int xcd = blockIdx.x & 7;
    const int idx = blockIdx.x >> 3;          // 0..1023
    const int bt = xcd * 4 + (idx >> 8);
    const int s = bt & 3;
    const int pb = (idx >> 1) & 127;
    const int ob = idx & 1;
    const int p0 = pb * 32;

    __shared__ __align__(16) ushort_t AsAll[2 * 8192];   // 32KB
    __shared__ __align__(16) ushort_t BsAll[2 * 2048];   // 8KB

    const int tid = threadIdx.x;
    const int w = tid >> 6, lane = tid & 63;
    const int wr = w >> 1, wc = w & 1;
    const int li = lane & 15, lk = lane >> 4;
    const int arow = wr * 32;
    const int bp = wc * 16 + li;
    int a_sl[2], b_sl[2];
#pragma unroll
    for (int h = 0; h < 2; ++h) {
        a_sl[h] = (((h * 4 + lk) ^ (li & 7)) << 3);
        b_sl[h] = (((h * 4 + lk) ^ SWZ(bp)) << 3);
    }

    const int sk = tid >> 3, spb = (tid & 7) * 4;
    // fragment-major emission constants (threads 0..255):
    const int eft = tid >> 6;                 // 0..3: (ptile_local, ktile_local)
    const int epl = ((eft >> 1) << 4) | li;   // p within 32-tile
    const int ekc = ((eft & 1) << 2) | lk;    // k-chunk 0..7 within 64k step

    const float* Bx = x + (size_t)bt * C_ * HW_ + p0 + spb;

    f32x4 acc[2];
    acc[0] = 0.f; acc[1] = 0.f;
    float4 nb;

#define STAGE_A8(T, BUF)                                                     \
    { const ushort_t* _tp = Wqk_pre + ((size_t)(s * 8 + (T)) << 14)          \
                            + (ob << 13);                                    \
      ushort_t* _ld = &AsAll[(BUF) * 8192];                                  \
      _Pragma("unroll")                                                      \
      for (int _i = 0; _i < 2; ++_i)                                         \
          GLOAD16(_tp + ((w * 2 + _i) << 9) + (lane << 3),                   \
                  _ld + ((w * 2 + _i) << 9)); }

#define LOAD_B8(T) nb = *reinterpret_cast<const float4*>(Bx + (size_t)((T) * 64 + sk) * HW_)

#define WRITE_B8(BUF)                                                        \
    { float _vv[4] = {nb.x, nb.y, nb.z, nb.w};                               \
      _Pragma("unroll")                                                      \
      for (int _j = 0; _j < 4; ++_j) {                                       \
          int _p = spb + _j;                                                 \
          BsAll[(BUF) * 2048 + _p * 64 + (((sk >> 3) ^ SWZ(_p)) << 3)        \
                + (sk & 7)] = f2bf(_vv[_j]);                                 \
      } }

#define EMIT8F(T, BUF)                                                       \
    if (ob == 0 && w < 4) {                                                  \
        s16x8 _ev = *reinterpret_cast<const s16x8*>(                         \
            &BsAll[(BUF) * 2048 + epl * 64 + ((ekc ^ SWZ(epl)) << 3)]);      \
        *reinterpret_cast<s16x8*>(                                           \
            xbfF + (((((size_t)bt * 256) + (p0 >> 4) + (eft >> 1)) * 16      \
                     + (T) * 2 + (eft & 1)) << 9) + lane * 8) = _ev;         \
    }

#define COMPUTE8(BUF)                                                        \
    { const int _ab = (BUF) * 8192, _bb = (BUF) * 2048;                      \
      _Pragma("unroll")                                                      \
      for (int h = 0; h < 2; ++h) {                                          \
          s16x8 af0 = *reinterpret_cast<const s16x8*>(                       \
              &AsAll[_ab + (arow + 0 * 16 + li) * 64 + a_sl[h]]);            \
          s16x8 af1 = *reinterpret_cast<const s16x8*>(                       \
              &AsAll[_ab + (arow + 1 * 16 + li) * 64 + a_sl[h]]);            \
          s16x8 bf = *reinterpret_cast<const s16x8*>(                        \
              &BsAll[_bb + bp * 64 + b_sl[h]]);                              \
          __builtin_amdgcn_s_setprio(1);                                     \
          acc[0] = MFMA16(af0, bf, acc[0]);                                  \
          acc[1] = MFMA16(af1, bf, acc[1]);                                  \
          __builtin_amdgcn_s_setprio(0);                                     \
      } }

    // prologue
    LOAD_B8(0);
    STAGE_A8(0, 0);
    WRITE_B8(0);
    VMCNT0; LGK0;
    __builtin_amdgcn_s_barrier();

#pragma unroll
    for (int t = 0; t < 8; ++t) {
        if (t < 7) { LOAD_B8(t + 1); STAGE_A8(t + 1, (t + 1) & 1); }
        EMIT8F(t, t & 1);
        COMPUTE8(t & 1);
        if (t < 7) {
            WRITE_B8((t + 1) & 1);
            VMCNT0; LGK0;
            __builtin_amdgcn_s_barrier();
        }
    }

#undef STAGE_A8
#undef LOAD_B8
#undef WRITE_B8
#undef EMIT8F
#undef COMPUTE8

    // epilogue: +bias, ob selects Q vs K (block-uniform)
    ushort_t* outp = ob ? Kb : Qb;
    const float* biasp = ob ? (bk + s * 128) : (bq + s * 128);
#pragma unroll
    for (int mf = 0; mf < 2; ++mf) {
#pragma unroll
        for (int r = 0; r < 4; ++r) {
            int m = arow + mf * 16 + lk * 4 + r;     // 0..127 within half
            float vv = acc[mf][r] + biasp[m];
            int p = p0 + wc * 16 + li;
            outp[(size_t)bt * D_ + (size_t)m * HW_ + p] = f2bf(vv);
        }
    }
}

// ===========================================================================
// vblend10: B-operand DIRECT global->VGPR from fragment-major xbfF (one
// coalesced 1KB load per frag, depth-1 register ping-pong prefetch,
// compiler-tracked) -- no B LDS, no B barrier coupling. A stays
// gload_lds + ds_read, triple-buffered stage-ahead-2 with counted vmcnt:
// in-flight at barrier = A(ts+2)x2 + B(ts+1)x4 -> VMCNT(6) (tail: 4).
// LDS 24KB; per-step LDS traffic 64KB -> 24KB.
// ===========================================================================
__global__ __launch_bounds__(256, 4) void vblend10(
    const ushort_t* __restrict__ Wvb_pre, const ushort_t* __restrict__ xbfF,
    const float* __restrict__ x, const float* __restrict__ bv,
    const float* __restrict__ att, const float* __restrict__ gamma,
    float* __restrict__ out) {

    // 4096 blocks: xcd = b (8); idx: pblk(64) x cblk(8), cblk innermost
    const int b = blockIdx.x & 7;
    const int idx = blockIdx.x >> 3;        // 0..511
    const int cblk = idx & 7;               // inner -> co-resident share B
    const int pblk = idx >> 3;              // 0..63
    const int p0 = pblk * 64;
    const int ct = cblk >> 2;
    const int csub = cblk & 3;

    __shared__ __align__(16) ushort_t AsAll[3 * 4096];   // 24KB (A only)

    const int tid = threadIdx.x;
    const int w = tid >> 6, lane = tid & 63;
    const int wr2 = w >> 1, wc2 = w & 1;
    const int li = lane & 15, lk = lane >> 4;

    int a_sl[2];
#pragma unroll
    for (int h = 0; h < 2; ++h)
        a_sl[h] = (((h * 4 + lk) ^ (li & 7)) << 3);

    float attv[16];
#pragma unroll
    for (int i = 0; i < 16; ++i)
        attv[i] = __uint_as_float(__builtin_amdgcn_readfirstlane(
            __float_as_uint(att[b * 16 + i])));

    f32x4 acc[2][2];
    f32x4 mst[4][2][2];
#pragma unroll
    for (int mf = 0; mf < 2; ++mf)
#pragma unroll
        for (int nf = 0; nf < 2; ++nf) acc[mf][nf] = 0.f;
#pragma unroll
    for (int so = 0; so < 4; ++so)
#pragma unroll
        for (int mf = 0; mf < 2; ++mf)
#pragma unroll
            for (int nf = 0; nf < 2; ++nf) mst[so][mf][nf] = 0.f;

    s16x8 bE[4], bO[4];   // B-frag ping-pong [h*2+nf]; all indices literal

#define STAGE_A10(TS, BUF)                                                   \
    {   const int _t = (TS) >> 3, _kt = (TS) & 7;                            \
        const ushort_t* _ap = Wvb_pre +                                      \
            (((size_t)(_t * 2 + ct) * 8 + _kt) << 14) + (csub << 12);        \
        ushort_t* _al = &AsAll[(BUF) * 4096];                                \
        GLOAD16(_ap + (w << 9) + (lane << 3), _al + (w << 9));               \
        GLOAD16(_ap + 2048 + (w << 9) + (lane << 3), _al + 2048 + (w << 9)); \
    }

// base frag index (x16-domain): (bt*256 + pblk*4 + wc2*2 + nf)*16 + (ts&7)*2 + h
#define LOADB10(TS, DST)                                                     \
    {   const size_t _fb = (((size_t)(b * 4 + ((TS) >> 3)) * 256             \
                            + pblk * 4 + wc2 * 2) * 16 + ((TS) & 7) * 2);    \
        _Pragma("unroll")                                                    \
        for (int _h = 0; _h < 2; ++_h)                                       \
            _Pragma("unroll")                                                \
            for (int _nf = 0; _nf < 2; ++_nf)                                \
                DST[_h * 2 + _nf] = *reinterpret_cast<const s16x8*>(         \
                    xbfF + ((_fb + _nf * 16 + _h) << 9) + lane * 8);         \
    }

#define COMPUTE10(BUF, SRC)                                                  \
    {   const int _ab = (BUF) * 4096;                                        \
        _Pragma("unroll")                                                    \
        for (int h = 0; h < 2; ++h) {                                        \
            s16x8 af0 = *reinterpret_cast<const s16x8*>(                     \
                &AsAll[_ab + (wr2 * 32 + 0 * 16 + li) * 64 + a_sl[h]]);      \
            s16x8 af1 = *reinterpret_cast<const s16x8*>(                     \
                &AsAll[_ab + (wr2 * 32 + 1 * 16 + li) * 64 + a_sl[h]]);      \
            __builtin_amdgcn_s_setprio(1);                                   \
            acc[0][0] = MFMA16(af0, SRC[h * 2 + 0], acc[0][0]);              \
            acc[0][1] = MFMA16(af0, SRC[h * 2 + 1], acc[0][1]);              \
            acc[1][0] = MFMA16(af1, SRC[h * 2 + 0], acc[1][0]);              \
            acc[1][1] = MFMA16(af1, SRC[h * 2 + 1], acc[1][1]);              \
            __builtin_amdgcn_s_setprio(0);                                   \
        } }

#define BLEND10(T2)                                                          \
    { _Pragma("unroll")                                                      \
      for (int _so = 0; _so < 4; ++_so)                                      \
          _Pragma("unroll")                                                  \
          for (int _mf = 0; _mf < 2; ++_mf)                                  \
              _Pragma("unroll")                                              \
              for (int _nf = 0; _nf < 2; ++_nf)                              \
                  mst[_so][_mf][_nf] += attv[_so * 4 + (T2)] * acc[_mf][_nf];\
      _Pragma("unroll")                                                      \
      for (int _mf = 0; _mf < 2; ++_mf)                                      \
          _Pragma("unroll")                                                  \
          for (int _nf = 0; _nf < 2; ++_nf) acc[_mf][_nf] = 0.f; }

    // prologue: A(0),A(1) staged; B(0) in regs. VMCNT(6) drains A(0) only.
    STAGE_A10(0, 0);
    STAGE_A10(1, 1);
    LOADB10(0, bE);
    VMCNT(6);
    __builtin_amdgcn_s_barrier();

#pragma unroll
    for (int ts = 0; ts < 32; ts += 2) {
        // even step ts: compute bE, prefetch bO
        if (ts + 2 < 32) STAGE_A10(ts + 2, (ts + 2) % 3);
        LOADB10(ts + 1, bO);
        COMPUTE10(ts % 3, bE);
        if (ts < 30) { VMCNT(6); } else { VMCNT(4); }
        __builtin_amdgcn_s_barrier();
        // odd step ts+1: compute bO, prefetch bE
        if (ts + 3 < 32) STAGE_A10(ts + 3, (ts + 3) % 3);
        if (ts + 2 < 32) LOADB10(ts + 2, bE);
        COMPUTE10((ts + 1) % 3, bO);
        if (ts + 1 == 7)  BLEND10(0);
        if (ts + 1 == 15) BLEND10(1);
        if (ts + 1 == 23) BLEND10(2);
        if (ts + 1 == 31) BLEND10(3);
        if (ts + 1 < 31) {
            VMCNT(6);
            __builtin_amdgcn_s_barrier();
        }
    }

#undef STAGE_A10
#undef LOADB10
#undef COMPUTE10
#undef BLEND10

    // epilogue: out = gm*(mst + sum_t att*bv) + x
    const float gm = gamma[0];
    const int c0 = cblk * 64;
#pragma unroll
    for (int mf = 0; mf < 2; ++mf) {
#pragma unroll
        for (int r = 0; r < 4; ++r) {
            int c = c0 + wr2 * 32 + mf * 16 + lk * 4 + r;
            float bvv[4];
#pragma unroll
            for (int t = 0; t < 4; ++t) bvv[t] = bv[(size_t)t * 512 + c];
#pragma unroll
            for (int so = 0; so < 4; ++so) {
                float bsum = attv[so * 4 + 0] * bvv[0] + attv[so * 4 + 1] * bvv[1]
                           + attv[so * 4 + 2] * bvv[2] + attv[so * 4 + 3] * bvv[3];
#pragma unroll
                for (int nf = 0; nf < 2; ++nf) {
                    int p = p0 + wc2 * 32 + nf * 16 + li;
                    size_t off = ((size_t)(b * 4 + so) * C_ + c) * HW_ + p;
                    out[off] = gm * (mst[so][mf][nf][r] + bsum) + x[off];
                }
            }
        }
    }
}

// ---------------------------------------------------------------------------
// gram5: all 24 reductions per (b, D/16-slice); Q/K read once. Deterministic.
// ---------------------------------------------------------------------------
__global__ __launch_bounds__(256) void gram5(
    const ushort_t* __restrict__ Q, const ushort_t* __restrict__ K,
    float* __restrict__ g4) {

    const int ch = blockIdx.x;       // 0..15
    const int b  = blockIdx.y;       // 0..7
    const size_t base = (size_t)ch * (D_ / 16);

    const uint4* qv[4];
    const uint4* kv[4];
#pragma unroll
    for (int s = 0; s < 4; ++s) {
        qv[s] = reinterpret_cast<const uint4*>(Q + (size_t)(b * 4 + s) * D_ + base);
        kv[s] = reinterpret_cast<const uint4*>(K + (size_t)(b * 4 + s) * D_ + base);
    }

    float accr[24];
#pragma unroll
    for (int e = 0; e < 24; ++e) accr[e] = 0.f;

    const int n8 = (int)(D_ / 16 / 8);
    for (int i = threadIdx.x; i < n8; i += 256) {
        uint4 qa[4], ka[4];
#pragma unroll
        for (int s = 0; s < 4; ++s) { qa[s] = qv[s][i]; ka[s] = kv[s][i]; }
#pragma unroll
        for (int s = 0; s < 4; ++s) {
#pragma unroll
            for (int u = 0; u < 4; ++u) accr[s * 4 + u] += dot8(qa[s], ka[u]);
            accr[16 + s] += dot8(qa[s], qa[s]);
            accr[20 + s] += dot8(ka[s], ka[s]);
        }
    }

    __shared__ float red[4][24];
    const int lane = threadIdx.x & 63, wid = threadIdx.x >> 6;
#pragma unroll
    for (int e = 0; e < 24; ++e) {
        float v = accr[e];
#pragma unroll
        for (int o = 32; o > 0; o >>= 1) v += __shfl_down(v, o);
        if (lane == 0) red[wid][e] = v;
    }
    __syncthreads();
    if (threadIdx.x < 24) {
        float t = red[0][threadIdx.x] + red[1][threadIdx.x]
                + red[2][threadIdx.x] + red[3][threadIdx.x];
        g4[((size_t)b * 24 + threadIdx.x) * 16 + ch] = t;
    }
}

__global__ void att_k5(const float* __restrict__ g4, float* __restrict__ att) {
    const int b = threadIdx.x;
    if (b >= B_) return;
    float e_[24];
#pragma unroll
    for (int e = 0; e < 24; ++e) {
        const float* p = g4 + ((size_t)b * 24 + e) * 16;
        float t = 0.f;
#pragma unroll
        for (int ch = 0; ch < 16; ++ch) t += p[ch];
        e_[e] = t;
    }
    float nq[4], nk[4];
#pragma unroll
    for (int s = 0; s < 4; ++s) {
        nq[s] = sqrtf(e_[16 + s]) + EPS_F;
        nk[s] = sqrtf(e_[20 + s]) + EPS_F;
    }
#pragma unroll
    for (int s = 0; s < 4; ++s) {
        float e[4], m = -1e30f;
#pragma unroll
        for (int t = 0; t < 4; ++t) {
            e[t] = e_[s * 4 + t] / (nq[s] * nk[t]);
            m = fmaxf(m, e[t]);
        }
        float sum = 0.f;
#pragma unroll
        for (int t = 0; t < 4; ++t) { e[t] = expf(e[t] - m); sum += e[t]; }
#pragma unroll
        for (int t = 0; t < 4; ++t) att[(size_t)(b * 4 + s) * 4 + t] = e[t] / sum;
    }
}

extern "C" void kernel_launch(void* const* d_in, const int* in_sizes, int n_in,
                              void* d_out, int out_size, void* d_ws, size_t ws_size,
                              hipStream_t stream) {
    const float* x     = (const float*)d_in[0];
    const float* wq    = (const float*)d_in[1];
    const float* bq    = (const float*)d_in[2];
    const float* wk    = (const float*)d_in[3];
    const float* bk    = (const float*)d_in[4];
    const float* wv    = (const float*)d_in[5];
    const float* bv    = (const float*)d_in[6];
    const float* gamma = (const float*)d_in[7];
    float* out = (float*)d_out;

    char* ws = (char*)d_ws;
    const size_t qk_elems = (size_t)B_ * S_ * Cq_ * HW_;       // 16,777,216
    ushort_t* Qb      = (ushort_t*)ws;                          // 33.55 MB
    ushort_t* Kb      = Qb + qk_elems;                          // 33.55 MB
    ushort_t* Wqk_pre = Kb + qk_elems;                          // 1.05 MB
    ushort_t* Wvb_pre = Wqk_pre + (size_t)4 * 8 * 256 * 64;     // 4.19 MB
    float*    g4      = (float*)(Wvb_pre + (size_t)4 * 2 * 8 * 256 * 64);
    float*    att     = g4 + 8 * 24 * 16;
    ushort_t* xbfF    = (ushort_t*)(att + 128);                 // 134.2 MB

    prep3<<<768, 256, 0, stream>>>(wq, wk, wv, Wqk_pre, Wvb_pre, g4);
    qk8f<<<8192, 512, 0, stream>>>(Wqk_pre, x, bq, bk, Qb, Kb, xbfF);
    gram5<<<dim3(16, 8), 256, 0, stream>>>(Qb, Kb, g4);
    att_k5<<<1, 64, 0, stream>>>(g4, att);
    vblend10<<<4096, 256, 0, stream>>>(Wvb_pre, xbfF, x, bv, att, gamma, out);
}

// Round 11
// 403.928 us; speedup vs baseline: 1.0796x; 1.0796x over previous
//
#include <hip/hip_runtime.h>
#include <hip/hip_bf16.h>

#define EPS_F 1e-10f

typedef short s16x8 __attribute__((ext_vector_type(8)));
typedef float f32x4 __attribute__((ext_vector_type(4)));
typedef unsigned short ushort_t;

constexpr int B_ = 8, S_ = 4, C_ = 512, Cq_ = 128, HW_ = 4096;
constexpr long long D_ = (long long)Cq_ * HW_;

__device__ inline float bf_lo(unsigned int u) { return __uint_as_float(u << 16); }
__device__ inline float bf_hi(unsigned int u) { return __uint_as_float(u & 0xffff0000u); }

__device__ inline ushort_t f2bf(float f) {
    __hip_bfloat16 h = __float2bfloat16(f);
    return *reinterpret_cast<ushort_t*>(&h);
}
__device__ inline unsigned int pack_bf2(float a, float b) {
    return (unsigned int)f2bf(a) | ((unsigned int)f2bf(b) << 16);
}
__device__ inline float dot8(uint4 a, uint4 b) {
    return bf_lo(a.x) * bf_lo(b.x) + bf_hi(a.x) * bf_hi(b.x)
         + bf_lo(a.y) * bf_lo(b.y) + bf_hi(a.y) * bf_hi(b.y)
         + bf_lo(a.z) * bf_lo(b.z) + bf_hi(a.z) * bf_hi(b.z)
         + bf_lo(a.w) * bf_lo(b.w) + bf_hi(a.w) * bf_hi(b.w);
}

#define GLOAD16(gp, lp) __builtin_amdgcn_global_load_lds( \
    (const __attribute__((address_space(1))) unsigned int*)(gp), \
    (__attribute__((address_space(3))) unsigned int*)(lp), 16, 0, 0)

#define VMCNT(n) asm volatile("s_waitcnt vmcnt(" #n ")" ::: "memory")
#define VMCNT0 asm volatile("s_waitcnt vmcnt(0)" ::: "memory")
#define LGK0   asm volatile("s_waitcnt lgkmcnt(0)" ::: "memory")
#define MFMA16(a, b, c) __builtin_amdgcn_mfma_f32_16x16x32_bf16(a, b, c, 0, 0, 0)

// swizzle involution over 8 chunk slots, p in [0,64)
#define SWZ(p) ((((p) >> 3) & 7) ^ ((p) & 7))

// ---------------------------------------------------------------------------
// prep3: fp32->bf16 weights, pre-swizzled (chunk slot = c ^ (row&7)) so
// global_load_lds (linear dest) + swizzled ds_read_b128 is conflict-free.
// Also zeroes g4.
// ---------------------------------------------------------------------------
__global__ __launch_bounds__(256) void prep3(
    const float* __restrict__ wq, const float* __restrict__ wk,
    const float* __restrict__ wv,
    ushort_t* __restrict__ Wqk_pre, ushort_t* __restrict__ Wvb_pre,
    float* __restrict__ g4) {
    int gid = blockIdx.x * 256 + threadIdx.x;
    if (gid < 8 * 24 * 16) g4[gid] = 0.f;
    if (gid < 65536) {                      // Wqk chunks
        int s = gid >> 14;
        int kt = (gid >> 11) & 7;
        int row = (gid >> 3) & 255;
        int slot = gid & 7;
        int col = kt * 64 + ((slot ^ (row & 7)) << 3);
        const float* src = (row < 128)
            ? &wq[((size_t)s * 128 + row) * 512 + col]
            : &wk[((size_t)s * 128 + (row - 128)) * 512 + col];
        float4 f0 = *reinterpret_cast<const float4*>(src);
        float4 f1 = *reinterpret_cast<const float4*>(src + 4);
        uint4 o;
        o.x = pack_bf2(f0.x, f0.y); o.y = pack_bf2(f0.z, f0.w);
        o.z = pack_bf2(f1.x, f1.y); o.w = pack_bf2(f1.z, f1.w);
        *reinterpret_cast<uint4*>(Wqk_pre + (size_t)gid * 8) = o;
    } else {                                 // Wvb chunks
        int c2 = gid - 65536;                // < 131072
        int t = c2 >> 15;
        int ct = (c2 >> 14) & 1;
        int kt = (c2 >> 11) & 7;
        int row = (c2 >> 3) & 255;
        int slot = c2 & 7;
        int col = kt * 64 + ((slot ^ (row & 7)) << 3);
        const float* src = &wv[((size_t)t * 512 + ct * 256 + row) * 512 + col];
        float4 f0 = *reinterpret_cast<const float4*>(src);
        float4 f1 = *reinterpret_cast<const float4*>(src + 4);
        uint4 o;
        o.x = pack_bf2(f0.x, f0.y); o.y = pack_bf2(f0.z, f0.w);
        o.z = pack_bf2(f1.x, f1.y); o.w = pack_bf2(f1.z, f1.w);
        *reinterpret_cast<uint4*>(Wvb_pre + (size_t)c2 * 8) = o;
    }
}

// ===========================================================================
// qk9: qk8 with T14 async-split staging -- WRITE_B moved BEFORE compute
// (legal: target buffer (t+1)&1 was last read in step t-1, barrier passed),
// gated by VMCNT(2) which drains ONLY the B register load and leaves the two
// A gload_lds in flight under EMIT+COMPUTE. Emits LINEAR xbfT (r8 layout).
// Block = 128o x 32p, BK=64, 512 thr; 64 VGPR, 40KB -> 4 blk x 8 waves/CU.
// ===========================================================================
__global__ __launch_bounds__(512, 8) void qk9(
    const ushort_t* __restrict__ Wqk_pre, const float* __restrict__ x,
    const float* __restrict__ bq, const float* __restrict__ bk,
    ushort_t* __restrict__ Qb, ushort_t* __restrict__ Kb,
    ushort_t* __restrict__ xbfT) {

    // 8192 blocks: xcd = blk&7 (== b); idx: t(4) x p(128) x o(2), o innermost
    const int xcd = blockIdx.x & 7;
    const int idx = blockIdx.x >> 3;          // 0..1023
    const int bt = xcd * 4 + (idx >> 8);
    const int s = bt & 3;
    const int pb = (idx >> 1) & 127;
    const int ob = idx & 1;
    const int p0 = pb * 32;

    __shared__ __align__(16) ushort_t AsAll[2 * 8192];   // 32KB
    __shared__ __align__(16) ushort_t BsAll[2 * 2048];   // 8KB

    const int tid = threadIdx.x;
    const int w = tid >> 6, lane = tid & 63;
    const int wr = w >> 1, wc = w & 1;
    const int li = lane & 15, lk = lane >> 4;
    const int arow = wr * 32;
    const int bp = wc * 16 + li;
    int a_sl[2], b_sl[2];
#pragma unroll
    for (int h = 0; h < 2; ++h) {
        a_sl[h] = (((h * 4 + lk) ^ (li & 7)) << 3);
        b_sl[h] = (((h * 4 + lk) ^ SWZ(bp)) << 3);
    }

    const int sk = tid >> 3, spb = (tid & 7) * 4;
    const int ep = tid >> 3, esl = tid & 7;
    const int ec = esl ^ SWZ(ep);

    const float* Bx = x + (size_t)bt * C_ * HW_ + p0 + spb;

    f32x4 acc[2];
    acc[0] = 0.f; acc[1] = 0.f;
    float4 nb;

#define STAGE_A9(T, BUF)                                                     \
    { const ushort_t* _tp = Wqk_pre + ((size_t)(s * 8 + (T)) << 14)          \
                            + (ob << 13);                                    \
      ushort_t* _ld = &AsAll[(BUF) * 8192];                                  \
      _Pragma("unroll")                                                      \
      for (int _i = 0; _i < 2; ++_i)                                         \
          GLOAD16(_tp + ((w * 2 + _i) << 9) + (lane << 3),                   \
                  _ld + ((w * 2 + _i) << 9)); }

#define LOAD_B9(T) nb = *reinterpret_cast<const float4*>(Bx + (size_t)((T) * 64 + sk) * HW_)

#define WRITE_B9(BUF)                                                        \
    { float _vv[4] = {nb.x, nb.y, nb.z, nb.w};                               \
      _Pragma("unroll")                                                      \
      for (int _j = 0; _j < 4; ++_j) {                                       \
          int _p = spb + _j;                                                 \
          BsAll[(BUF) * 2048 + _p * 64 + (((sk >> 3) ^ SWZ(_p)) << 3)        \
                + (sk & 7)] = f2bf(_vv[_j]);                                 \
      } }

#define EMIT9(T, BUF)                                                        \
    if (ob == 0 && w < 4) {                                                  \
        s16x8 _ev = *reinterpret_cast<const s16x8*>(&BsAll[(BUF) * 2048 + tid * 8]); \
        *reinterpret_cast<s16x8*>(                                           \
            xbfT + ((size_t)bt * HW_ + p0 + ep) * 512 + (T) * 64 + ec * 8) = _ev; \
    }

#define COMPUTE9(BUF)                                                        \
    { const int _ab = (BUF) * 8192, _bb = (BUF) * 2048;                      \
      _Pragma("unroll")                                                      \
      for (int h = 0; h < 2; ++h) {                                          \
          s16x8 af0 = *reinterpret_cast<const s16x8*>(                       \
              &AsAll[_ab + (arow + 0 * 16 + li) * 64 + a_sl[h]]);            \
          s16x8 af1 = *reinterpret_cast<const s16x8*>(                       \
              &AsAll[_ab + (arow + 1 * 16 + li) * 64 + a_sl[h]]);            \
          s16x8 bf = *reinterpret_cast<const s16x8*>(                        \
              &BsAll[_bb + bp * 64 + b_sl[h]]);                              \
          __builtin_amdgcn_s_setprio(1);                                     \
          acc[0] = MFMA16(af0, bf, acc[0]);                                  \
          acc[1] = MFMA16(af1, bf, acc[1]);                                  \
          __builtin_amdgcn_s_setprio(0);                                     \
      } }

    // prologue: tile 0 staged + written, drained
    LOAD_B9(0);
    STAGE_A9(0, 0);
    VMCNT(2);
    WRITE_B9(0);
    VMCNT0; LGK0;
    __builtin_amdgcn_s_barrier();

#pragma unroll
    for (int t = 0; t < 8; ++t) {
        // async-split: issue next-tile loads, drain ONLY the B reg-load,
        // convert+ds_write early; A gloads + ds ops complete under compute.
        if (t < 7) {
            LOAD_B9(t + 1);
            STAGE_A9(t + 1, (t + 1) & 1);
            VMCNT(2);                       // queue: [B-ld, glA, glA] -> B done
            WRITE_B9((t + 1) & 1);
        }
        EMIT9(t, t & 1);
        COMPUTE9(t & 1);
        if (t < 7) {
            VMCNT0; LGK0;                   // drain A gloads + ds writes/reads
            __builtin_amdgcn_s_barrier();
        }
    }

#undef STAGE_A9
#undef LOAD_B9
#undef WRITE_B9
#undef EMIT9
#undef COMPUTE9

    // epilogue: +bias, ob selects Q vs K (block-uniform)
    ushort_t* outp = ob ? Kb : Qb;
    const float* biasp = ob ? (bk + s * 128) : (bq + s * 128);
#pragma unroll
    for (int mf = 0; mf < 2; ++mf) {
#pragma unroll
        for (int r = 0; r < 4; ++r) {
            int m = arow + mf * 16 + lk * 4 + r;     // 0..127 within half
            float vv = acc[mf][r] + biasp[m];
            int p = p0 + wc * 16 + li;
            outp[(size_t)bt * D_ + (size_t)m * HW_ + p] = f2bf(vv);
        }
    }
}

// ===========================================================================
// vblend8 (r8 champion, verbatim): fused V-GEMM + blend + bias + gamma +
// residual. 64c x 64p block tile, 256 thr, cblk innermost (L2 B-sharing),
// both operands via global_load_lds, 2-phase drain. 230 us measured.
// ===========================================================================
__global__ __launch_bounds__(256, 4) void vblend8(
    const ushort_t* __restrict__ Wvb_pre, const ushort_t* __restrict__ xbfT,
    const float* __restrict__ x, const float* __restrict__ bv,
    const float* __restrict__ att, const float* __restrict__ gamma,
    float* __restrict__ out) {

    // 4096 blocks: xcd = b (8); idx: pblk(64) x cblk(8), cblk innermost
    const int b = blockIdx.x & 7;
    const int idx = blockIdx.x >> 3;        // 0..511
    const int cblk = idx & 7;               // 0..7  (inner -> shared B)
    const int p0 = (idx >> 3) * 64;         // 0..63 p-tiles
    const int ct = cblk >> 2;
    const int csub = cblk & 3;

    __shared__ __align__(16) ushort_t AsAll[2 * 4096];   // 16KB
    __shared__ __align__(16) ushort_t BsAll[2 * 4096];   // 16KB

    const int tid = threadIdx.x;
    const int w = tid >> 6, lane = tid & 63;
    const int wr2 = w >> 1, wc2 = w & 1;
    const int li = lane & 15, lk = lane >> 4;

    int a_sl[2], b_sl[2];
    const int bp = wc2 * 32 + li;
    const int bp1 = bp + 16;
    int b_sl1[2];
#pragma unroll
    for (int h = 0; h < 2; ++h) {
        a_sl[h] = (((h * 4 + lk) ^ (li & 7)) << 3);
        b_sl[h] = (((h * 4 + lk) ^ SWZ(bp)) << 3);
        b_sl1[h] = (((h * 4 + lk) ^ SWZ(bp1)) << 3);
    }

    float attv[16];
#pragma unroll
    for (int i = 0; i < 16; ++i)
        attv[i] = __uint_as_float(__builtin_amdgcn_readfirstlane(
            __float_as_uint(att[b * 16 + i])));

    const int bst_p0 = tid >> 3, bst_sl0 = tid & 7;
    const int bst_c0 = bst_sl0 ^ SWZ(bst_p0);
    const int bst_p1 = (tid + 256) >> 3, bst_sl1 = tid & 7;
    const int bst_c1 = bst_sl1 ^ SWZ(bst_p1);

    f32x4 acc[2][2];
    f32x4 mst[4][2][2];
#pragma unroll
    for (int mf = 0; mf < 2; ++mf)
#pragma unroll
        for (int nf = 0; nf < 2; ++nf) acc[mf][nf] = 0.f;
#pragma unroll
    for (int so = 0; so < 4; ++so)
#pragma unroll
        for (int mf = 0; mf < 2; ++mf)
#pragma unroll
            for (int nf = 0; nf < 2; ++nf) mst[so][mf][nf] = 0.f;

#define STAGE7(TS, BUF)                                                      \
    {   const int _t = (TS) >> 3, _kt = (TS) & 7;                            \
        const ushort_t* _ap = Wvb_pre +                                      \
            (((size_t)(_t * 2 + ct) * 8 + _kt) << 14) + (csub << 12);        \
        ushort_t* _al = &AsAll[(BUF) * 4096];                                \
        GLOAD16(_ap + (size_t)(w << 9) + (size_t)(lane << 3),                \
                _al + (w << 9));                                             \
        GLOAD16(_ap + 2048 + (size_t)(w << 9) + (size_t)(lane << 3),         \
                _al + 2048 + (w << 9));                                      \
        const ushort_t* _bb = xbfT + ((size_t)(b * 4 + _t) * HW_);           \
        GLOAD16(_bb + ((size_t)(p0 + bst_p0)) * 512 + _kt * 64 + bst_c0 * 8, \
                &BsAll[(BUF) * 4096 + (w << 9)]);                            \
        GLOAD16(_bb + ((size_t)(p0 + bst_p1)) * 512 + _kt * 64 + bst_c1 * 8, \
                &BsAll[(BUF) * 4096 + 2048 + (w << 9)]);                     \
    }

#define COMPUTE7(BUF)                                                       \
    {   const int _ab = (BUF) * 4096, _bbf = (BUF) * 4096;                  \
        _Pragma("unroll")                                                    \
        for (int h = 0; h < 2; ++h) {                                        \
            s16x8 af0 = *reinterpret_cast<const s16x8*>(                     \
                &AsAll[_ab + (wr2 * 32 + 0 * 16 + li) * 64 + a_sl[h]]);      \
            s16x8 af1 = *reinterpret_cast<const s16x8*>(                     \
                &AsAll[_ab + (wr2 * 32 + 1 * 16 + li) * 64 + a_sl[h]]);      \
            s16x8 bf0 = *reinterpret_cast<const s16x8*>(                     \
                &BsAll[_bbf + bp * 64 + b_sl[h]]);                           \
            s16x8 bf1 = *reinterpret_cast<const s16x8*>(                     \
                &BsAll[_bbf + bp1 * 64 + b_sl1[h]]);                         \
            __builtin_amdgcn_s_setprio(1);                                   \
            acc[0][0] = MFMA16(af0, bf0, acc[0][0]);                         \
            acc[0][1] = MFMA16(af0, bf1, acc[0][1]);                         \
            acc[1][0] = MFMA16(af1, bf0, acc[1][0]);                         \
            acc[1][1] = MFMA16(af1, bf1, acc[1][1]);                         \
            __builtin_amdgcn_s_setprio(0);                                   \
        } }

#define BLEND7(T2)                                                           \
    { _Pragma("unroll")                                                      \
      for (int _so = 0; _so < 4; ++_so)                                      \
          _Pragma("unroll")                                                  \
          for (int _mf = 0; _mf < 2; ++_mf)                                  \
              _Pragma("unroll")                                              \
              for (int _nf = 0; _nf < 2; ++_nf)                              \
                  mst[_so][_mf][_nf] += attv[_so * 4 + (T2)] * acc[_mf][_nf];\
      _Pragma("unroll")                                                      \
      for (int _mf = 0; _mf < 2; ++_mf)                                      \
          _Pragma("unroll")                                                  \
          for (int _nf = 0; _nf < 2; ++_nf) acc[_mf][_nf] = 0.f; }

    STAGE7(0, 0);
    VMCNT0;
    __builtin_amdgcn_s_barrier();

#pragma unroll
    for (int ts = 0; ts < 32; ++ts) {
        if (ts < 31) STAGE7(ts + 1, (ts + 1) & 1);
        COMPUTE7(ts & 1);
        if (ts == 7)  BLEND7(0);
        if (ts == 15) BLEND7(1);
        if (ts == 23) BLEND7(2);
        if (ts == 31) BLEND7(3);
        if (ts < 31) {
            VMCNT0;
            __builtin_amdgcn_s_barrier();
        }
    }

#undef STAGE7
#undef COMPUTE7
#undef BLEND7

    const float gm = gamma[0];
    const int c0 = cblk * 64;
#pragma unroll
    for (int mf = 0; mf < 2; ++mf) {
#pragma unroll
        for (int r = 0; r < 4; ++r) {
            int c = c0 + wr2 * 32 + mf * 16 + lk * 4 + r;
            float bvv[4];
#pragma unroll
            for (int t = 0; t < 4; ++t) bvv[t] = bv[(size_t)t * 512 + c];
#pragma unroll
            for (int so = 0; so < 4; ++so) {
                float bsum = attv[so * 4 + 0] * bvv[0] + attv[so * 4 + 1] * bvv[1]
                           + attv[so * 4 + 2] * bvv[2] + attv[so * 4 + 3] * bvv[3];
#pragma unroll
                for (int nf = 0; nf < 2; ++nf) {
                    int p = p0 + wc2 * 32 + nf * 16 + li;
                    size_t off = ((size_t)(b * 4 + so) * C_ + c) * HW_ + p;
                    out[off] = gm * (mst[so][mf][nf][r] + bsum) + x[off];
                }
            }
        }
    }
}

// ---------------------------------------------------------------------------
// gram5: all 24 reductions per (b, D/16-slice); Q/K read once. Deterministic.
// ---------------------------------------------------------------------------
__global__ __launch_bounds__(256) void gram5(
    const ushort_t* __restrict__ Q, const ushort_t* __restrict__ K,
    float* __restrict__ g4) {

    const int ch = blockIdx.x;       // 0..15
    const int b  = blockIdx.y;       // 0..7
    const size_t base = (size_t)ch * (D_ / 16);

    const uint4* qv[4];
    const uint4* kv[4];
#pragma unroll
    for (int s = 0; s < 4; ++s) {
        qv[s] = reinterpret_cast<const uint4*>(Q + (size_t)(b * 4 + s) * D_ + base);
        kv[s] = reinterpret_cast<const uint4*>(K + (size_t)(b * 4 + s) * D_ + base);
    }

    float accr[24];
#pragma unroll
    for (int e = 0; e < 24; ++e) accr[e] = 0.f;

    const int n8 = (int)(D_ / 16 / 8);
    for (int i = threadIdx.x; i < n8; i += 256) {
        uint4 qa[4], ka[4];
#pragma unroll
        for (int s = 0; s < 4; ++s) { qa[s] = qv[s][i]; ka[s] = kv[s][i]; }
#pragma unroll
        for (int s = 0; s < 4; ++s) {
#pragma unroll
            for (int u = 0; u < 4; ++u) accr[s * 4 + u] += dot8(qa[s], ka[u]);
            accr[16 + s] += dot8(qa[s], qa[s]);
            accr[20 + s] += dot8(ka[s], ka[s]);
        }
    }

    __shared__ float red[4][24];
    const int lane = threadIdx.x & 63, wid = threadIdx.x >> 6;
#pragma unroll
    for (int e = 0; e < 24; ++e) {
        float v = accr[e];
#pragma unroll
        for (int o = 32; o > 0; o >>= 1) v += __shfl_down(v, o);
        if (lane == 0) red[wid][e] = v;
    }
    __syncthreads();
    if (threadIdx.x < 24) {
        float t = red[0][threadIdx.x] + red[1][threadIdx.x]
                + red[2][threadIdx.x] + red[3][threadIdx.x];
        g4[((size_t)b * 24 + threadIdx.x) * 16 + ch] = t;
    }
}

__global__ void att_k5(const float* __restrict__ g4, float* __restrict__ att) {
    const int b = threadIdx.x;
    if (b >= B_) return;
    float e_[24];
#pragma unroll
    for (int e = 0; e < 24; ++e) {
        const float* p = g4 + ((size_t)b * 24 + e) * 16;
        float t = 0.f;
#pragma unroll
        for (int ch = 0; ch < 16; ++ch) t += p[ch];
        e_[e] = t;
    }
    float nq[4], nk[4];
#pragma unroll
    for (int s = 0; s < 4; ++s) {
        nq[s] = sqrtf(e_[16 + s]) + EPS_F;
        nk[s] = sqrtf(e_[20 + s]) + EPS_F;
    }
#pragma unroll
    for (int s = 0; s < 4; ++s) {
        float e[4], m = -1e30f;
#pragma unroll
        for (int t = 0; t < 4; ++t) {
            e[t] = e_[s * 4 + t] / (nq[s] * nk[t]);
            m = fmaxf(m, e[t]);
        }
        float sum = 0.f;
#pragma unroll
        for (int t = 0; t < 4; ++t) { e[t] = expf(e[t] - m); sum += e[t]; }
#pragma unroll
        for (int t = 0; t < 4; ++t) att[(size_t)(b * 4 + s) * 4 + t] = e[t] / sum;
    }
}

extern "C" void kernel_launch(void* const* d_in, const int* in_sizes, int n_in,
                              void* d_out, int out_size, void* d_ws, size_t ws_size,
                              hipStream_t stream) {
    const float* x     = (const float*)d_in[0];
    const float* wq    = (const float*)d_in[1];
    const float* bq    = (const float*)d_in[2];
    const float* wk    = (const float*)d_in[3];
    const float* bk    = (const float*)d_in[4];
    const float* wv    = (const float*)d_in[5];
    const float* bv    = (const float*)d_in[6];
    const float* gamma = (const float*)d_in[7];
    float* out = (float*)d_out;

    char* ws = (char*)d_ws;
    const size_t qk_elems = (size_t)B_ * S_ * Cq_ * HW_;       // 16,777,216
    ushort_t* Qb      = (ushort_t*)ws;                          // 33.55 MB
    ushort_t* Kb      = Qb + qk_elems;                          // 33.55 MB
    ushort_t* Wqk_pre = Kb + qk_elems;                          // 1.05 MB
    ushort_t* Wvb_pre = Wqk_pre + (size_t)4 * 8 * 256 * 64;     // 4.19 MB
    float*    g4      = (float*)(Wvb_pre + (size_t)4 * 2 * 8 * 256 * 64);
    float*    att     = g4 + 8 * 24 * 16;
    ushort_t* xbfT    = (ushort_t*)(att + 128);                 // 134.2 MB

    prep3<<<768, 256, 0, stream>>>(wq, wk, wv, Wqk_pre, Wvb_pre, g4);
    qk9<<<8192, 512, 0, stream>>>(Wqk_pre, x, bq, bk, Qb, Kb, xbfT);
    gram5<<<dim3(16, 8), 256, 0, stream>>>(Qb, Kb, g4);
    att_k5<<<1, 64, 0, stream>>>(g4, att);
    vblend8<<<4096, 256, 0, stream>>>(Wvb_pre, xbfT, x, bv, att, gamma, out);
}